// Round 2
// baseline (1070.598 us; speedup 1.0000x reference)
//
#include <hip/hip_runtime.h>

typedef __bf16 bf16;
typedef __attribute__((ext_vector_type(8))) __bf16 bf16x8;
typedef __attribute__((ext_vector_type(4))) float f32x4;

#define B_SZ 4
#define SEQ 2048
#define DM 1024
#define DIN 2048
#define NH 256
#define DSTATE 16
#define CONVD 2080
#define DPROJ 4384
#define NPAD1 4480
#define MROWS 8192

__device__ __forceinline__ void gload_lds16(const void* g, void* l) {
  __builtin_amdgcn_global_load_lds(
      (__attribute__((address_space(1))) void*)g,
      (__attribute__((address_space(3))) void*)l, 16, 0, 0);
}

// ---------------- transpose (f32 [K][N] -> bf16 [Npad][K], zero-pad rows >= N)
__global__ void transpose_cvt(const float* __restrict__ W, bf16* __restrict__ WT,
                              int K, int N, int Npad) {
  __shared__ float tile[32][33];
  int k0 = blockIdx.x * 32, n0 = blockIdx.y * 32;
  int tx = threadIdx.x, ty = threadIdx.y;  // (32, 8)
#pragma unroll
  for (int j = 0; j < 4; j++) {
    int k = k0 + ty + 8 * j, n = n0 + tx;
    tile[ty + 8 * j][tx] = (k < K && n < N) ? W[(size_t)k * N + n] : 0.f;
  }
  __syncthreads();
#pragma unroll
  for (int j = 0; j < 4; j++) {
    int n = n0 + ty + 8 * j, k = k0 + tx;
    if (n < Npad && k < K) WT[(size_t)n * K + k] = (bf16)tile[tx][ty + 8 * j];
  }
}

// ---------------- layernorm (f32 in) -> xn bf16
__global__ __launch_bounds__(256) void ln_kernel(const float* __restrict__ x,
                                                 const float* __restrict__ lw,
                                                 const float* __restrict__ lb,
                                                 bf16* __restrict__ xn) {
  int row = blockIdx.x;
  int t = threadIdx.x;
  f32x4 v4 = ((const f32x4*)(x + (size_t)row * DM))[t];
  float v0 = v4[0], v1 = v4[1], v2 = v4[2], v3 = v4[3];
  float s = v0 + v1 + v2 + v3;
  float s2 = v0 * v0 + v1 * v1 + v2 * v2 + v3 * v3;
#pragma unroll
  for (int off = 32; off > 0; off >>= 1) {
    s += __shfl_down(s, off);
    s2 += __shfl_down(s2, off);
  }
  __shared__ float ps[8];
  int wave = t >> 6, lane = t & 63;
  if (lane == 0) { ps[wave] = s; ps[4 + wave] = s2; }
  __syncthreads();
  s = ps[0] + ps[1] + ps[2] + ps[3];
  s2 = ps[4] + ps[5] + ps[6] + ps[7];
  float mean = s * (1.f / DM);
  float var = s2 * (1.f / DM) - mean * mean;
  float rstd = rsqrtf(var + 1e-5f);
  f32x4 wv = ((const f32x4*)lw)[t];
  f32x4 bv = ((const f32x4*)lb)[t];
  bf16x8 dummy;
  bf16* o = (bf16*)&dummy;
  o[0] = (bf16)((v0 - mean) * rstd * wv[0] + bv[0]);
  o[1] = (bf16)((v1 - mean) * rstd * wv[1] + bv[1]);
  o[2] = (bf16)((v2 - mean) * rstd * wv[2] + bv[2]);
  o[3] = (bf16)((v3 - mean) * rstd * wv[3] + bv[3]);
  bf16* dst = xn + (size_t)row * DM + t * 4;
  dst[0] = o[0]; dst[1] = o[1]; dst[2] = o[2]; dst[3] = o[3];
}

// ---------------- GEMM: A[M][K] bf16 @ BT[Npad][K] bf16 -> C
// EPI=0: C bf16 with col<N guard.  EPI=1: C f32 = Xres + acc (N==ldc).
template <int EPI>
__global__ __launch_bounds__(256) void gemm_kernel(const bf16* __restrict__ A,
                                                   const bf16* __restrict__ BT,
                                                   int K, int N, int ldc,
                                                   void* __restrict__ Cv,
                                                   const float* __restrict__ Xres) {
  __shared__ bf16 As[128 * 32];
  __shared__ bf16 Bs[128 * 32];
  int m0 = blockIdx.y * 128, n0 = blockIdx.x * 128;
  int t = threadIdx.x;
  int lane = t & 63, wave = t >> 6;
  int wm = wave >> 1, wn = wave & 1;
  int lr = lane & 15, kq = lane >> 4;

  f32x4 acc[4][4] = {};
  const char* Ab = (const char*)A;
  const char* Bb = (const char*)BT;
  size_t strideA = (size_t)K * 2;
  int r0 = t >> 2;
  int kb0 = (t & 3) * 16;
  int nk = K / 32;
  for (int kt = 0; kt < nk; ++kt) {
    size_t koff = (size_t)kt * 64;
    gload_lds16(Ab + (size_t)(m0 + r0) * strideA + koff + kb0, (char*)As + wave * 1024);
    gload_lds16(Ab + (size_t)(m0 + 64 + r0) * strideA + koff + kb0, (char*)As + 4096 + wave * 1024);
    gload_lds16(Bb + (size_t)(n0 + r0) * strideA + koff + kb0, (char*)Bs + wave * 1024);
    gload_lds16(Bb + (size_t)(n0 + 64 + r0) * strideA + koff + kb0, (char*)Bs + 4096 + wave * 1024);
    __syncthreads();
    bf16x8 af[4], bfr[4];
#pragma unroll
    for (int i = 0; i < 4; i++) af[i] = *(const bf16x8*)&As[(wm * 64 + i * 16 + lr) * 32 + kq * 8];
#pragma unroll
    for (int j = 0; j < 4; j++) bfr[j] = *(const bf16x8*)&Bs[(wn * 64 + j * 16 + lr) * 32 + kq * 8];
#pragma unroll
    for (int i = 0; i < 4; i++)
#pragma unroll
      for (int j = 0; j < 4; j++)
        acc[i][j] = __builtin_amdgcn_mfma_f32_16x16x32_bf16(af[i], bfr[j], acc[i][j], 0, 0, 0);
    __syncthreads();
  }
#pragma unroll
  for (int i = 0; i < 4; i++) {
    int row = m0 + wm * 64 + i * 16 + kq * 4;
#pragma unroll
    for (int j = 0; j < 4; j++) {
      int col = n0 + wn * 64 + j * 16 + lr;
#pragma unroll
      for (int r = 0; r < 4; r++) {
        if constexpr (EPI == 0) {
          bf16* C = (bf16*)Cv;
          if (col < N) C[(size_t)(row + r) * ldc + col] = (bf16)acc[i][j][r];
        } else {
          float* C = (float*)Cv;
          size_t o = (size_t)(row + r) * ldc + col;
          C[o] = Xres[o] + acc[i][j][r];
        }
      }
    }
  }
}

// ---------------- conv(4-tap causal depthwise) + silu for 2080 ch, softplus(dt)
__global__ __launch_bounds__(256) void conv_prep(const bf16* __restrict__ u,
                                                 const float* __restrict__ cw,
                                                 const float* __restrict__ cb,
                                                 const float* __restrict__ dt_bias,
                                                 bf16* __restrict__ xs,
                                                 float* __restrict__ BC,
                                                 float* __restrict__ dtf) {
  int idx = blockIdx.x * 256 + threadIdx.x;
  const int CW = CONVD + NH;  // 2336
  if (idx >= MROWS * CW) return;
  int row = idx / CW;
  int c = idx - row * CW;
  int t = row & (SEQ - 1);
  if (c < CONVD) {
    float acc = cb[c];
#pragma unroll
    for (int j = 0; j < 4; j++) {
      int tt = t - 3 + j;
      if (tt >= 0)
        acc += cw[j * CONVD + c] * (float)u[(size_t)(row - 3 + j) * DPROJ + DIN + c];
    }
    float sv = acc / (1.f + __expf(-acc));
    if (c < DIN) xs[(size_t)row * DIN + c] = (bf16)sv;
    else BC[(size_t)row * 32 + (c - DIN)] = sv;
  } else {
    int h = c - CONVD;
    float xv = (float)u[(size_t)row * DPROJ + (DPROJ - NH) + h] + dt_bias[h];
    float sp = (xv > 20.f) ? xv : log1pf(__expf(xv));
    dtf[(size_t)row * NH + h] = sp;
  }
}

// ---------------- sequential SSM scan; lane owns (head-slot, p), 16 states in regs
__global__ __launch_bounds__(64) void scan_kernel(const bf16* __restrict__ xs,
                                                  const float* __restrict__ BC,
                                                  const float* __restrict__ dtf,
                                                  const float* __restrict__ A_log,
                                                  const float* __restrict__ Dp,
                                                  bf16* __restrict__ y) {
  int blk = blockIdx.x;  // 128 = 4 b * 32 head-groups
  int b = blk >> 5;
  int hb = (blk & 31) * 8;  // 8 heads per wave
  int lane = threadIdx.x;
  int hh = lane >> 3;  // head slot 0..7
  int h = hb + hh;
  float A = -__expf(A_log[h]);
  float D = Dp[h];
  float st[16];
#pragma unroll
  for (int n = 0; n < 16; n++) st[n] = 0.f;
  size_t rb = (size_t)b * SEQ;
  for (int t = 0; t < SEQ; t++) {
    size_t row = rb + t;
    const float* bcrow = BC + row * 32;
    float dtv = dtf[row * NH + h];
    float x = (float)xs[row * DIN + hb * 8 + lane];
    float dA = __expf(dtv * A);
    float w = dtv * x;
    float yv = 0.f;
#pragma unroll
    for (int n = 0; n < 16; n++) {
      st[n] = st[n] * dA + w * bcrow[n];
      yv += st[n] * bcrow[16 + n];
    }
    y[row * DIN + hb * 8 + lane] = (bf16)(yv + D * x);
  }
}

// ---------------- gating + rmsnorm -> g bf16
__global__ __launch_bounds__(256) void gate_rms(const bf16* __restrict__ u,
                                                const bf16* __restrict__ y,
                                                const float* __restrict__ rms_w,
                                                bf16* __restrict__ g) {
  int row = blockIdx.x;
  int t = threadIdx.x;
  bf16x8 zv = ((const bf16x8*)(u + (size_t)row * DPROJ))[t];
  bf16x8 yv = ((const bf16x8*)(y + (size_t)row * DIN))[t];
  float gv[8];
  float s2 = 0.f;
#pragma unroll
  for (int i = 0; i < 8; i++) {
    float z = (float)zv[i];
    float yy = (float)yv[i];
    float gg = yy * z / (1.f + __expf(-z));
    gv[i] = gg;
    s2 += gg * gg;
  }
#pragma unroll
  for (int off = 32; off > 0; off >>= 1) s2 += __shfl_down(s2, off);
  __shared__ float ps[4];
  int wave = t >> 6, lane = t & 63;
  if (lane == 0) ps[wave] = s2;
  __syncthreads();
  s2 = ps[0] + ps[1] + ps[2] + ps[3];
  float scale = rsqrtf(s2 * (1.f / DIN) + 1e-5f);
  f32x4 w0 = ((const f32x4*)rms_w)[2 * t];
  f32x4 w1 = ((const f32x4*)rms_w)[2 * t + 1];
  bf16x8 og;
#pragma unroll
  for (int i = 0; i < 4; i++) og[i] = (bf16)(gv[i] * scale * w0[i]);
#pragma unroll
  for (int i = 0; i < 4; i++) og[4 + i] = (bf16)(gv[4 + i] * scale * w1[i]);
  ((bf16x8*)(g + (size_t)row * DIN))[t] = og;
}

extern "C" void kernel_launch(void* const* d_in, const int* in_sizes, int n_in,
                              void* d_out, int out_size, void* d_ws, size_t ws_size,
                              hipStream_t stream) {
  const float* x = (const float*)d_in[0];
  const float* lnw = (const float*)d_in[1];
  const float* lnb = (const float*)d_in[2];
  const float* Win = (const float*)d_in[3];
  const float* cw = (const float*)d_in[4];
  const float* cb = (const float*)d_in[5];
  const float* Alog = (const float*)d_in[6];
  const float* Dpv = (const float*)d_in[7];
  const float* dtb = (const float*)d_in[8];
  const float* rmsw = (const float*)d_in[9];
  const float* Wout = (const float*)d_in[10];
  float* out = (float*)d_out;

  char* ws = (char*)d_ws;
  // lifetime-overlapped layout, peak 152.6 MB
  bf16* u = (bf16*)(ws + 0);                     // [8192][4384] bf16, 71,827,456
  bf16* xnb = (bf16*)(ws + 71827456);            // [8192][1024] bf16, 16,777,216 (dead after GEMM1)
  bf16* WinT = (bf16*)(ws + 88604672);           // [4480][1024] bf16,  9,175,040 (dead after GEMM1)
  bf16* yb = (bf16*)(ws + 71827456);             // [8192][2048] bf16, 33,554,432 (reuses xnb+WinT)
  bf16* xsb = (bf16*)(ws + 105381888);           // [8192][2048] bf16, 33,554,432 (dead after scan)
  bf16* gb = (bf16*)(ws + 105381888);            // reuses xsb
  float* BC = (float*)(ws + 138936320);          // [8192][32] f32,     1,048,576
  float* dtf = (float*)(ws + 139984896);         // [8192][256] f32,    8,388,608
  bf16* WoutT = (bf16*)(ws + 148373504);         // [1024][2048] bf16,  4,194,304

  transpose_cvt<<<dim3(32, 140), dim3(32, 8), 0, stream>>>(Win, WinT, 1024, DPROJ, NPAD1);
  transpose_cvt<<<dim3(64, 32), dim3(32, 8), 0, stream>>>(Wout, WoutT, DIN, DM, DM);
  ln_kernel<<<MROWS, 256, 0, stream>>>(x, lnw, lnb, xnb);
  gemm_kernel<0><<<dim3(NPAD1 / 128, MROWS / 128), 256, 0, stream>>>(xnb, WinT, DM, DPROJ, DPROJ, u, nullptr);
  conv_prep<<<(MROWS * (CONVD + NH)) / 256, 256, 0, stream>>>(u, cw, cb, dtb, xsb, BC, dtf);
  scan_kernel<<<128, 64, 0, stream>>>(xsb, BC, dtf, Alog, Dpv, yb);
  gate_rms<<<MROWS, 256, 0, stream>>>(u, yb, rmsw, gb);
  gemm_kernel<1><<<dim3(DM / 128, MROWS / 128), 256, 0, stream>>>(gb, WoutT, DIN, DM, DM, out, x);
}

// Round 3
// 360.418 us; speedup vs baseline: 2.9704x; 2.9704x over previous
//
#include <hip/hip_runtime.h>

typedef __bf16 bf16;
typedef __attribute__((ext_vector_type(8))) __bf16 bf16x8;
typedef __attribute__((ext_vector_type(4))) float f32x4;

#define B_SZ 4
#define SEQ 2048
#define DM 1024
#define DIN 2048
#define NH 256
#define DSTATE 16
#define CONVD 2080
#define DPROJ 4384
#define NPAD1 4480
#define MROWS 8192
#define NC 64
#define LC 32
#define UROWB 8768  // u row stride in bytes (4384 * 2)

__device__ __forceinline__ void gload_lds16(const void* g, void* l) {
  __builtin_amdgcn_global_load_lds(
      (__attribute__((address_space(1))) void*)g,
      (__attribute__((address_space(3))) void*)l, 16, 0, 0);
}

// ---------------- transpose (f32 [K][N] -> bf16 [Npad][K], zero-pad rows >= N)
__global__ void transpose_cvt(const float* __restrict__ W, bf16* __restrict__ WT,
                              int K, int N, int Npad) {
  __shared__ float tile[32][33];
  int k0 = blockIdx.x * 32, n0 = blockIdx.y * 32;
  int tx = threadIdx.x, ty = threadIdx.y;  // (32, 8)
#pragma unroll
  for (int j = 0; j < 4; j++) {
    int k = k0 + ty + 8 * j, n = n0 + tx;
    tile[ty + 8 * j][tx] = (k < K && n < N) ? W[(size_t)k * N + n] : 0.f;
  }
  __syncthreads();
#pragma unroll
  for (int j = 0; j < 4; j++) {
    int n = n0 + ty + 8 * j, k = k0 + tx;
    if (n < Npad && k < K) WT[(size_t)n * K + k] = (bf16)tile[tx][ty + 8 * j];
  }
}

// ---------------- layernorm (f32 in) -> xn bf16
__global__ __launch_bounds__(256) void ln_kernel(const float* __restrict__ x,
                                                 const float* __restrict__ lw,
                                                 const float* __restrict__ lb,
                                                 bf16* __restrict__ xn) {
  int row = blockIdx.x;
  int t = threadIdx.x;
  f32x4 v4 = ((const f32x4*)(x + (size_t)row * DM))[t];
  float v0 = v4[0], v1 = v4[1], v2 = v4[2], v3 = v4[3];
  float s = v0 + v1 + v2 + v3;
  float s2 = v0 * v0 + v1 * v1 + v2 * v2 + v3 * v3;
#pragma unroll
  for (int off = 32; off > 0; off >>= 1) {
    s += __shfl_down(s, off);
    s2 += __shfl_down(s2, off);
  }
  __shared__ float ps[8];
  int wave = t >> 6, lane = t & 63;
  if (lane == 0) { ps[wave] = s; ps[4 + wave] = s2; }
  __syncthreads();
  s = ps[0] + ps[1] + ps[2] + ps[3];
  s2 = ps[4] + ps[5] + ps[6] + ps[7];
  float mean = s * (1.f / DM);
  float var = s2 * (1.f / DM) - mean * mean;
  float rstd = rsqrtf(var + 1e-5f);
  f32x4 wv = ((const f32x4*)lw)[t];
  f32x4 bv = ((const f32x4*)lb)[t];
  bf16 o[4];
  o[0] = (bf16)((v0 - mean) * rstd * wv[0] + bv[0]);
  o[1] = (bf16)((v1 - mean) * rstd * wv[1] + bv[1]);
  o[2] = (bf16)((v2 - mean) * rstd * wv[2] + bv[2]);
  o[3] = (bf16)((v3 - mean) * rstd * wv[3] + bv[3]);
  bf16* dst = xn + (size_t)row * DM + t * 4;
  dst[0] = o[0]; dst[1] = o[1]; dst[2] = o[2]; dst[3] = o[3];
}

// ---------------- GEMM: A[M][K] bf16 @ BT[Npad][K] bf16 -> C
// EPI=0: C bf16 with col<N guard.  EPI=1: C f32 = Xres + acc (N==ldc).
template <int EPI>
__global__ __launch_bounds__(256) void gemm_kernel(const bf16* __restrict__ A,
                                                   const bf16* __restrict__ BT,
                                                   int K, int N, int ldc,
                                                   void* __restrict__ Cv,
                                                   const float* __restrict__ Xres) {
  __shared__ bf16 As[128 * 32];
  __shared__ bf16 Bs[128 * 32];
  int m0 = blockIdx.y * 128, n0 = blockIdx.x * 128;
  int t = threadIdx.x;
  int lane = t & 63, wave = t >> 6;
  int wm = wave >> 1, wn = wave & 1;
  int lr = lane & 15, kq = lane >> 4;

  f32x4 acc[4][4] = {};
  const char* Ab = (const char*)A;
  const char* Bb = (const char*)BT;
  size_t strideA = (size_t)K * 2;
  int r0 = t >> 2;
  int kb0 = (t & 3) * 16;
  int nk = K / 32;
  for (int kt = 0; kt < nk; ++kt) {
    size_t koff = (size_t)kt * 64;
    gload_lds16(Ab + (size_t)(m0 + r0) * strideA + koff + kb0, (char*)As + wave * 1024);
    gload_lds16(Ab + (size_t)(m0 + 64 + r0) * strideA + koff + kb0, (char*)As + 4096 + wave * 1024);
    gload_lds16(Bb + (size_t)(n0 + r0) * strideA + koff + kb0, (char*)Bs + wave * 1024);
    gload_lds16(Bb + (size_t)(n0 + 64 + r0) * strideA + koff + kb0, (char*)Bs + 4096 + wave * 1024);
    __syncthreads();
    bf16x8 af[4], bfr[4];
#pragma unroll
    for (int i = 0; i < 4; i++) af[i] = *(const bf16x8*)&As[(wm * 64 + i * 16 + lr) * 32 + kq * 8];
#pragma unroll
    for (int j = 0; j < 4; j++) bfr[j] = *(const bf16x8*)&Bs[(wn * 64 + j * 16 + lr) * 32 + kq * 8];
#pragma unroll
    for (int i = 0; i < 4; i++)
#pragma unroll
      for (int j = 0; j < 4; j++)
        acc[i][j] = __builtin_amdgcn_mfma_f32_16x16x32_bf16(af[i], bfr[j], acc[i][j], 0, 0, 0);
    __syncthreads();
  }
#pragma unroll
  for (int i = 0; i < 4; i++) {
    int row = m0 + wm * 64 + i * 16 + kq * 4;
#pragma unroll
    for (int j = 0; j < 4; j++) {
      int col = n0 + wn * 64 + j * 16 + lr;
#pragma unroll
      for (int r = 0; r < 4; r++) {
        if constexpr (EPI == 0) {
          bf16* C = (bf16*)Cv;
          if (col < N) C[(size_t)(row + r) * ldc + col] = (bf16)acc[i][j][r];
        } else {
          float* C = (float*)Cv;
          size_t o = (size_t)(row + r) * ldc + col;
          C[o] = Xres[o] + acc[i][j][r];
        }
      }
    }
  }
}

// ---------------- conv(4-tap causal depthwise) + silu for 2080 ch, softplus(dt)
__global__ __launch_bounds__(256) void conv_prep(const bf16* __restrict__ u,
                                                 const float* __restrict__ cw,
                                                 const float* __restrict__ cb,
                                                 const float* __restrict__ dt_bias,
                                                 bf16* __restrict__ xs,
                                                 float* __restrict__ BC,
                                                 float* __restrict__ dtf) {
  int idx = blockIdx.x * 256 + threadIdx.x;
  const int CW = CONVD + NH;  // 2336
  if (idx >= MROWS * CW) return;
  int row = idx / CW;
  int c = idx - row * CW;
  int t = row & (SEQ - 1);
  if (c < CONVD) {
    float acc = cb[c];
#pragma unroll
    for (int j = 0; j < 4; j++) {
      int tt = t - 3 + j;
      if (tt >= 0)
        acc += cw[j * CONVD + c] * (float)u[(size_t)(row - 3 + j) * DPROJ + DIN + c];
    }
    float sv = acc / (1.f + __expf(-acc));
    if (c < DIN) xs[(size_t)row * DIN + c] = (bf16)sv;
    else BC[(size_t)row * 32 + (c - DIN)] = sv;
  } else {
    int h = c - CONVD;
    float xv = (float)u[(size_t)row * DPROJ + (DPROJ - NH) + h] + dt_bias[h];
    float sp = (xv > 20.f) ? xv : log1pf(__expf(xv));
    dtf[(size_t)row * NH + h] = sp;
  }
}

// ---------------- chunked scan, phase 1: local scan from zero -> (S, P) in u's dead tail
// block = (b, hg, c): blockIdx.x = b*2048 + hg*64 + c.  Slot: u_row[blockIdx.x] bytes [4096, 8224)
__global__ __launch_bounds__(64) void scan_p1(const bf16* __restrict__ xs,
                                              const float* __restrict__ BC,
                                              const float* __restrict__ dtf,
                                              const float* __restrict__ A_log,
                                              bf16* __restrict__ uscr) {
  int c = blockIdx.x & 63, hg = (blockIdx.x >> 6) & 31, b = blockIdx.x >> 11;
  int lane = threadIdx.x, hh = lane >> 3;
  int h = hg * 8 + hh;
  float A = -__expf(A_log[h]);
  float st[16];
#pragma unroll
  for (int n = 0; n < 16; n++) st[n] = 0.f;
  float pcum = 1.f;
  size_t rb = (size_t)b * SEQ + (size_t)c * LC;
  for (int t = 0; t < LC; t++) {
    size_t row = rb + t;
    const float* bcrow = BC + row * 32;
    float dtv = dtf[row * NH + h];
    float x = (float)xs[row * DIN + hg * 64 + lane];
    float dA = __expf(dtv * A);
    pcum *= dA;
    float w = dtv * x;
#pragma unroll
    for (int n = 0; n < 16; n++) st[n] = st[n] * dA + w * bcrow[n];
  }
  char* slot = (char*)uscr + (size_t)blockIdx.x * UROWB + 4096;
  float* S = (float*)slot;
#pragma unroll
  for (int n = 0; n < 16; n++) S[lane * 16 + n] = st[n];
  if ((lane & 7) == 0) ((float*)(slot + 4096))[hh] = pcum;
}

// ---------------- phase 2: sequential combine over chunks; overwrite S with incoming H
__global__ __launch_bounds__(64) void scan_p2(bf16* __restrict__ uscr) {
  int bh = blockIdx.x;  // 0..127 = b*32+hg
  int lane = threadIdx.x, hh = lane >> 3;
  float H[16];
#pragma unroll
  for (int n = 0; n < 16; n++) H[n] = 0.f;
  for (int c = 0; c < NC; c++) {
    char* slot = (char*)uscr + ((size_t)bh * NC + c) * UROWB + 4096;
    float* S = (float*)slot;
    float s[16];
#pragma unroll
    for (int n = 0; n < 16; n++) s[n] = S[lane * 16 + n];
    float P = ((const float*)(slot + 4096))[hh];
#pragma unroll
    for (int n = 0; n < 16; n++) {
      float hn = H[n];
      S[lane * 16 + n] = hn;       // incoming state for chunk c
      H[n] = P * hn + s[n];
    }
  }
}

// ---------------- phase 3: re-scan each chunk from true incoming state, emit y
__global__ __launch_bounds__(64) void scan_p3(const bf16* __restrict__ xs,
                                              const float* __restrict__ BC,
                                              const float* __restrict__ dtf,
                                              const float* __restrict__ A_log,
                                              const float* __restrict__ Dp,
                                              const bf16* __restrict__ uscr,
                                              bf16* __restrict__ y) {
  int c = blockIdx.x & 63, hg = (blockIdx.x >> 6) & 31, b = blockIdx.x >> 11;
  int lane = threadIdx.x, hh = lane >> 3;
  int h = hg * 8 + hh;
  float A = -__expf(A_log[h]);
  float D = Dp[h];
  const char* slot = (const char*)uscr + (size_t)blockIdx.x * UROWB + 4096;
  float st[16];
#pragma unroll
  for (int n = 0; n < 16; n++) st[n] = ((const float*)slot)[lane * 16 + n];
  size_t rb = (size_t)b * SEQ + (size_t)c * LC;
  for (int t = 0; t < LC; t++) {
    size_t row = rb + t;
    const float* bcrow = BC + row * 32;
    float dtv = dtf[row * NH + h];
    float x = (float)xs[row * DIN + hg * 64 + lane];
    float dA = __expf(dtv * A);
    float w = dtv * x;
    float yv = 0.f;
#pragma unroll
    for (int n = 0; n < 16; n++) {
      st[n] = st[n] * dA + w * bcrow[n];
      yv += st[n] * bcrow[16 + n];
    }
    y[row * DIN + hg * 64 + lane] = (bf16)(yv + D * x);
  }
}

// ---------------- gating + rmsnorm -> g bf16
__global__ __launch_bounds__(256) void gate_rms(const bf16* __restrict__ u,
                                                const bf16* __restrict__ y,
                                                const float* __restrict__ rms_w,
                                                bf16* __restrict__ g) {
  int row = blockIdx.x;
  int t = threadIdx.x;
  bf16x8 zv = ((const bf16x8*)(u + (size_t)row * DPROJ))[t];
  bf16x8 yv = ((const bf16x8*)(y + (size_t)row * DIN))[t];
  float gv[8];
  float s2 = 0.f;
#pragma unroll
  for (int i = 0; i < 8; i++) {
    float z = (float)zv[i];
    float yy = (float)yv[i];
    float gg = yy * z / (1.f + __expf(-z));
    gv[i] = gg;
    s2 += gg * gg;
  }
#pragma unroll
  for (int off = 32; off > 0; off >>= 1) s2 += __shfl_down(s2, off);
  __shared__ float ps[4];
  int wave = t >> 6, lane = t & 63;
  if (lane == 0) ps[wave] = s2;
  __syncthreads();
  s2 = ps[0] + ps[1] + ps[2] + ps[3];
  float scale = rsqrtf(s2 * (1.f / DIN) + 1e-5f);
  f32x4 w0 = ((const f32x4*)rms_w)[2 * t];
  f32x4 w1 = ((const f32x4*)rms_w)[2 * t + 1];
  bf16x8 og;
#pragma unroll
  for (int i = 0; i < 4; i++) og[i] = (bf16)(gv[i] * scale * w0[i]);
#pragma unroll
  for (int i = 0; i < 4; i++) og[4 + i] = (bf16)(gv[4 + i] * scale * w1[i]);
  ((bf16x8*)(g + (size_t)row * DIN))[t] = og;
}

extern "C" void kernel_launch(void* const* d_in, const int* in_sizes, int n_in,
                              void* d_out, int out_size, void* d_ws, size_t ws_size,
                              hipStream_t stream) {
  const float* x = (const float*)d_in[0];
  const float* lnw = (const float*)d_in[1];
  const float* lnb = (const float*)d_in[2];
  const float* Win = (const float*)d_in[3];
  const float* cw = (const float*)d_in[4];
  const float* cb = (const float*)d_in[5];
  const float* Alog = (const float*)d_in[6];
  const float* Dpv = (const float*)d_in[7];
  const float* dtb = (const float*)d_in[8];
  const float* rmsw = (const float*)d_in[9];
  const float* Wout = (const float*)d_in[10];
  float* out = (float*)d_out;

  char* ws = (char*)d_ws;
  // lifetime-overlapped layout, peak 152.6 MB
  bf16* u = (bf16*)(ws + 0);                     // [8192][4384] bf16, 71,827,456
  bf16* xnb = (bf16*)(ws + 71827456);            // [8192][1024] bf16 (dead after GEMM1)
  bf16* WinT = (bf16*)(ws + 88604672);           // [4480][1024] bf16 (dead after GEMM1)
  bf16* yb = (bf16*)(ws + 71827456);             // [8192][2048] bf16 (reuses xnb+WinT)
  bf16* xsb = (bf16*)(ws + 105381888);           // [8192][2048] bf16 (dead after scan)
  bf16* gb = (bf16*)(ws + 105381888);            // reuses xsb
  float* BC = (float*)(ws + 138936320);          // [8192][32] f32
  float* dtf = (float*)(ws + 139984896);         // [8192][256] f32
  bf16* WoutT = (bf16*)(ws + 148373504);         // [1024][2048] bf16

  transpose_cvt<<<dim3(32, 140), dim3(32, 8), 0, stream>>>(Win, WinT, 1024, DPROJ, NPAD1);
  transpose_cvt<<<dim3(64, 32), dim3(32, 8), 0, stream>>>(Wout, WoutT, DIN, DM, DM);
  ln_kernel<<<MROWS, 256, 0, stream>>>(x, lnw, lnb, xnb);
  gemm_kernel<0><<<dim3(NPAD1 / 128, MROWS / 128), 256, 0, stream>>>(xnb, WinT, DM, DPROJ, DPROJ, u, nullptr);
  conv_prep<<<(MROWS * (CONVD + NH)) / 256, 256, 0, stream>>>(u, cw, cb, dtb, xsb, BC, dtf);
  scan_p1<<<MROWS, 64, 0, stream>>>(xsb, BC, dtf, Alog, u);
  scan_p2<<<128, 64, 0, stream>>>(u);
  scan_p3<<<MROWS, 64, 0, stream>>>(xsb, BC, dtf, Alog, Dpv, u, yb);
  gate_rms<<<MROWS, 256, 0, stream>>>(u, yb, rmsw, gb);
  gemm_kernel<1><<<dim3(DM / 128, MROWS / 128), 256, 0, stream>>>(gb, WoutT, DIN, DM, DM, out, x);
}